// Round 18
// baseline (569.087 us; speedup 1.0000x reference)
//
#include <hip/hip_runtime.h>
#include <hip/hip_bf16.h>
#include <math.h>

#define NL 2
#define NH 32
#define NKVH 8
#define HD 64
#define DM 2048
#define FF 8192
#define SEQ 1024
#define QKVW 3072
#define RMS_EPS 1e-5f
#define ROPE_BLOCKS (SEQ * (NH + NKVH) * 32 / 256)   // 5120

typedef short s8v __attribute__((ext_vector_type(8)));
typedef short s4v __attribute__((ext_vector_type(4)));
typedef float f32x4 __attribute__((ext_vector_type(4)));
typedef __hip_bfloat16 bf16;

// ---------------- embed gather ----------------
__global__ __launch_bounds__(256) void embed_kernel(const int* __restrict__ ids,
                                                    const float* __restrict__ emb,
                                                    float* __restrict__ x) {
    int s = blockIdx.x;
    int row = ids[s];
    const float4* src = (const float4*)(emb + (size_t)row * DM);
    float4* dst = (float4*)(x + (size_t)s * DM);
    #pragma unroll
    for (int i = 0; i < 2; ++i)
        dst[threadIdx.x + i * 256] = src[threadIdx.x + i * 256];
}

// ---------------- RMSNorm: f32 in, bf16 out ----------------
__global__ __launch_bounds__(256) void rms_kernel(const float* __restrict__ x,
                                                  const float* __restrict__ g,
                                                  bf16* __restrict__ out) {
    int s = blockIdx.x;
    const float4* row = (const float4*)(x + (size_t)s * DM);
    float4 v0 = row[threadIdx.x * 2];
    float4 v1 = row[threadIdx.x * 2 + 1];
    float ss = v0.x*v0.x + v0.y*v0.y + v0.z*v0.z + v0.w*v0.w
             + v1.x*v1.x + v1.y*v1.y + v1.z*v1.z + v1.w*v1.w;
    #pragma unroll
    for (int o = 32; o > 0; o >>= 1) ss += __shfl_down(ss, o, 64);
    __shared__ float red[4];
    if ((threadIdx.x & 63) == 0) red[threadIdx.x >> 6] = ss;
    __syncthreads();
    float total = red[0] + red[1] + red[2] + red[3];
    float inv = 1.0f / sqrtf(total / (float)DM + RMS_EPS);
    const float4* g4 = (const float4*)g;
    float4 ga = g4[threadIdx.x * 2], gb = g4[threadIdx.x * 2 + 1];
    union { bf16 h[8]; s8v v; } u;
    u.h[0] = __float2bfloat16(v0.x * inv * ga.x);
    u.h[1] = __float2bfloat16(v0.y * inv * ga.y);
    u.h[2] = __float2bfloat16(v0.z * inv * ga.z);
    u.h[3] = __float2bfloat16(v0.w * inv * ga.w);
    u.h[4] = __float2bfloat16(v1.x * inv * gb.x);
    u.h[5] = __float2bfloat16(v1.y * inv * gb.y);
    u.h[6] = __float2bfloat16(v1.z * inv * gb.z);
    u.h[7] = __float2bfloat16(v1.w * inv * gb.w);
    *(s8v*)(out + (size_t)s * DM + threadIdx.x * 8) = u.v;
}

// ---------------- fused split-K reduce + residual add + RMSNorm ----------------
__global__ __launch_bounds__(256) void reduce_rms_kernel(float* __restrict__ x,
                                                         const float* __restrict__ p,
                                                         int slices, size_t stride4,
                                                         const float* __restrict__ g,
                                                         bf16* __restrict__ out) {
    const int s = blockIdx.x, t = threadIdx.x;
    const size_t i0 = (size_t)s * (DM / 4) + t * 2;
    float4 v0 = ((const float4*)x)[i0];
    float4 v1 = ((const float4*)x)[i0 + 1];
    for (int c = 0; c < slices; ++c) {
        float4 a = ((const float4*)p)[i0 + c * stride4];
        float4 b = ((const float4*)p)[i0 + 1 + c * stride4];
        v0.x += a.x; v0.y += a.y; v0.z += a.z; v0.w += a.w;
        v1.x += b.x; v1.y += b.y; v1.z += b.z; v1.w += b.w;
    }
    ((float4*)x)[i0] = v0;
    ((float4*)x)[i0 + 1] = v1;
    float ss = v0.x*v0.x + v0.y*v0.y + v0.z*v0.z + v0.w*v0.w
             + v1.x*v1.x + v1.y*v1.y + v1.z*v1.z + v1.w*v1.w;
    #pragma unroll
    for (int o = 32; o > 0; o >>= 1) ss += __shfl_down(ss, o, 64);
    __shared__ float red[4];
    if ((t & 63) == 0) red[t >> 6] = ss;
    __syncthreads();
    float total = red[0] + red[1] + red[2] + red[3];
    float inv = 1.0f / sqrtf(total / (float)DM + RMS_EPS);
    const float4* g4 = (const float4*)g;
    float4 ga = g4[t * 2], gb = g4[t * 2 + 1];
    union { bf16 h[8]; s8v v; } u;
    u.h[0] = __float2bfloat16(v0.x * inv * ga.x);
    u.h[1] = __float2bfloat16(v0.y * inv * ga.y);
    u.h[2] = __float2bfloat16(v0.z * inv * ga.z);
    u.h[3] = __float2bfloat16(v0.w * inv * ga.w);
    u.h[4] = __float2bfloat16(v1.x * inv * gb.x);
    u.h[5] = __float2bfloat16(v1.y * inv * gb.y);
    u.h[6] = __float2bfloat16(v1.z * inv * gb.z);
    u.h[7] = __float2bfloat16(v1.w * inv * gb.w);
    *(s8v*)(out + (size_t)s * DM + t * 8) = u.v;
}

// ---------------- bf16 MFMA GEMM with in-kernel f32-weight transpose (128x128x64) ----------------
template<bool OUTBF>
__global__ __launch_bounds__(256) void gemm_f32w_kernel(const bf16* __restrict__ A, int Ka,
                                                        const float* __restrict__ Wa, int Na,
                                                        const float* __restrict__ Wb, int Nb,
                                                        const float* __restrict__ Wc,
                                                        float* __restrict__ C,
                                                        bf16* __restrict__ Cb,
                                                        int M, int N, int Kchunk) {
    __shared__ bf16 As[2][128 * 64];
    __shared__ bf16 Bs[2][128 * 64];
    const int t = threadIdx.x, lane = t & 63;
    const int w = t >> 6;
    const int m0 = blockIdx.y * 128, n0 = blockIdx.x * 128;
    const size_t koff = (size_t)blockIdx.z * Kchunk;

    const int nl = t & 127;
    const int kob = t >> 7;
    const int ng = n0 + nl;
    const float* wp; int wstr;
    if (ng < Na)           { wp = Wa + ng;             wstr = Na; }
    else if (ng < Na + Nb) { wp = Wb + (ng - Na);      wstr = Nb; }
    else                   { wp = Wc + (ng - Na - Nb); wstr = N - Na - Nb; }
    wp += koff * (size_t)wstr;

    const int ako = t & 7, am = t >> 3;
    const bf16* apt = A + (size_t)(m0 + am) * Ka + koff + ako * 8;

    const int wm = (w >> 1) * 64, wn = (w & 1) * 64;
    const int fr = lane & 15, sl = lane >> 4;

    f32x4 acc[4][4];
    f32x4 z = {0.f, 0.f, 0.f, 0.f};
    #pragma unroll
    for (int i = 0; i < 4; ++i)
        #pragma unroll
        for (int j = 0; j < 4; ++j) acc[i][j] = z;

    float rb[4][8];
    s8v ra[4];

    auto LOADR = [&](int tile) {
        const int k0 = tile * 64;
        #pragma unroll
        for (int u = 0; u < 4; ++u) {
            const float* p = wp + (size_t)(k0 + (kob + 2 * u) * 8) * wstr;
            #pragma unroll
            for (int j = 0; j < 8; ++j) rb[u][j] = p[(size_t)j * wstr];
            ra[u] = *(const s8v*)(apt + (size_t)(32 * u) * Ka + k0);
        }
    };
    auto WRITE = [&](bf16* AsB, bf16* BsB) {
        #pragma unroll
        for (int u = 0; u < 4; ++u) {
            union { bf16 h[8]; s8v v; } cv;
            #pragma unroll
            for (int j = 0; j < 8; ++j) cv.h[j] = __float2bfloat16(rb[u][j]);
            int ko = kob + 2 * u;
            *(s8v*)((char*)BsB + nl * 128 + ((ko * 16) ^ ((nl & 7) << 4))) = cv.v;
            int m = am + 32 * u;
            *(s8v*)((char*)AsB + m * 128 + ((ako * 16) ^ ((m & 7) << 4))) = ra[u];
        }
    };
    auto COMPUTE = [&](const bf16* AsB, const bf16* BsB) {
        #pragma unroll
        for (int kk = 0; kk < 2; ++kk) {
            const int kb = kk * 64 + sl * 16;
            s8v af[4], bfv[4];
            #pragma unroll
            for (int i = 0; i < 4; ++i) {
                int m = wm + i * 16 + fr;
                af[i] = *(const s8v*)((const char*)AsB + m * 128 + (kb ^ ((m & 7) << 4)));
            }
            #pragma unroll
            for (int j = 0; j < 4; ++j) {
                int n = wn + j * 16 + fr;
                bfv[j] = *(const s8v*)((const char*)BsB + n * 128 + (kb ^ ((n & 7) << 4)));
            }
            #pragma unroll
            for (int i = 0; i < 4; ++i)
                #pragma unroll
                for (int j = 0; j < 4; ++j)
                    acc[i][j] = __builtin_amdgcn_mfma_f32_16x16x32_bf16(af[i], bfv[j], acc[i][j], 0, 0, 0);
        }
    };

    const int nt = Kchunk / 64;
    LOADR(0);
    WRITE(&As[0][0], &Bs[0][0]);
    __syncthreads();
    for (int tt = 0; tt < nt; ++tt) {
        const int cur = tt & 1;
        if (tt + 1 < nt) LOADR(tt + 1);
        COMPUTE(&As[cur][0], &Bs[cur][0]);
        if (tt + 1 < nt) {
            __syncthreads();
            WRITE(&As[cur ^ 1][0], &Bs[cur ^ 1][0]);
            __syncthreads();
        }
    }

    float* Cz = C + (size_t)blockIdx.z * M * N;
    #pragma unroll
    for (int i = 0; i < 4; ++i) {
        #pragma unroll
        for (int j = 0; j < 4; ++j) {
            #pragma unroll
            for (int q = 0; q < 4; ++q) {
                int row = m0 + wm + i * 16 + sl * 4 + q;
                int col = n0 + wn + j * 16 + fr;
                float vv = acc[i][j][q];
                if constexpr (OUTBF) Cb[(size_t)row * N + col] = __float2bfloat16(vv);
                else                 Cz[(size_t)row * N + col] = vv;
            }
        }
    }
}

// ---------------- 256x256x64 8-wave GEMM, f32 weights in, f32 split-K partials (wo / down) ----------------
__global__ __launch_bounds__(512) void gemm256_kernel(const bf16* __restrict__ A, int Ka,
                                                      const float* __restrict__ Wa, int Na,
                                                      const float* __restrict__ Wb,
                                                      float* __restrict__ C,
                                                      int M, int N, int Kchunk) {
    __shared__ bf16 As[2][256 * 64];
    __shared__ bf16 Bs[2][256 * 64];
    const int t = threadIdx.x, lane = t & 63;
    const int w = t >> 6;
    const int m0 = blockIdx.y * 256, n0 = blockIdx.x * 256;
    const size_t koff = (size_t)blockIdx.z * Kchunk;

    const int nl = t & 255;
    const int kob = t >> 8;
    const int ng = n0 + nl;
    const float* wp; int wstr;
    if (ng < Na) { wp = Wa + ng;        wstr = Na; }
    else         { wp = Wb + (ng - Na); wstr = N - Na; }
    wp += koff * (size_t)wstr;

    const int ako = t & 7, am = t >> 3;
    const bf16* apt = A + (size_t)(m0 + am) * Ka + koff + ako * 8;

    const int wm = (w >> 2) * 128, wn = (w & 3) * 64;
    const int fr = lane & 15, sl = lane >> 4;

    f32x4 acc[8][4];
    f32x4 z = {0.f, 0.f, 0.f, 0.f};
    #pragma unroll
    for (int i = 0; i < 8; ++i)
        #pragma unroll
        for (int j = 0; j < 4; ++j) acc[i][j] = z;

    float rb[4][8];
    s8v ra[4];

    auto LOADR = [&](int tile) {
        const int k0 = tile * 64;
        #pragma unroll
        for (int u = 0; u < 4; ++u) {
            const float* p = wp + (size_t)(k0 + (kob + 2 * u) * 8) * wstr;
            #pragma unroll
            for (int j = 0; j < 8; ++j) rb[u][j] = p[(size_t)j * wstr];
            ra[u] = *(const s8v*)(apt + (size_t)(64 * u) * Ka + k0);
        }
    };
    auto WRITE = [&](bf16* AsB, bf16* BsB) {
        #pragma unroll
        for (int u = 0; u < 4; ++u) {
            union { bf16 h[8]; s8v v; } cv;
            #pragma unroll
            for (int j = 0; j < 8; ++j) cv.h[j] = __float2bfloat16(rb[u][j]);
            int ko = kob + 2 * u;
            *(s8v*)((char*)BsB + nl * 128 + ((ko * 16) ^ ((nl & 7) << 4))) = cv.v;
            int m = am + 64 * u;
            *(s8v*)((char*)AsB + m * 128 + ((ako * 16) ^ ((m & 7) << 4))) = ra[u];
        }
    };
    auto COMPUTE = [&](const bf16* AsB, const bf16* BsB) {
        #pragma unroll
        for (int kk = 0; kk < 2; ++kk) {
            const int kb = kk * 64 + sl * 16;
            s8v af[8], bfv[4];
            #pragma unroll
            for (int i = 0; i < 8; ++i) {
                int m = wm + i * 16 + fr;
                af[i] = *(const s8v*)((const char*)AsB + m * 128 + (kb ^ ((m & 7) << 4)));
            }
            #pragma unroll
            for (int j = 0; j < 4; ++j) {
                int n = wn + j * 16 + fr;
                bfv[j] = *(const s8v*)((const char*)BsB + n * 128 + (kb ^ ((n & 7) << 4)));
            }
            #pragma unroll
            for (int i = 0; i < 8; ++i)
                #pragma unroll
                for (int j = 0; j < 4; ++j)
                    acc[i][j] = __builtin_amdgcn_mfma_f32_16x16x32_bf16(af[i], bfv[j], acc[i][j], 0, 0, 0);
        }
    };

    const int nt = Kchunk / 64;
    LOADR(0);
    WRITE(&As[0][0], &Bs[0][0]);
    __syncthreads();
    for (int tt = 0; tt < nt; ++tt) {
        const int cur = tt & 1;
        if (tt + 1 < nt) LOADR(tt + 1);
        COMPUTE(&As[cur][0], &Bs[cur][0]);
        if (tt + 1 < nt) {
            __syncthreads();
            WRITE(&As[cur ^ 1][0], &Bs[cur ^ 1][0]);
            __syncthreads();
        }
    }

    float* Cz = C + (size_t)blockIdx.z * M * N;
    #pragma unroll
    for (int i = 0; i < 8; ++i) {
        #pragma unroll
        for (int j = 0; j < 4; ++j) {
            #pragma unroll
            for (int q = 0; q < 4; ++q) {
                int row = m0 + wm + i * 16 + sl * 4 + q;
                int col = n0 + wn + j * 16 + fr;
                Cz[(size_t)row * N + col] = acc[i][j][q];
            }
        }
    }
}

// ---------------- 256-wide gate|up GEMM with fused SiLU epilogue -> gab bf16 ----------------
__global__ __launch_bounds__(512) void gemm_gu_kernel(const bf16* __restrict__ A,
                                                      const float* __restrict__ Wg,
                                                      const float* __restrict__ Wu,
                                                      bf16* __restrict__ gab) {
    __shared__ char lds[131072];
    const int t = threadIdx.x, lane = t & 63;
    const int w = t >> 6;
    const int m0 = blockIdx.y * 256, n0g = blockIdx.x * 128;

    const int nl = t & 255;
    const int kob = t >> 8;
    const int cl = nl & 127;
    const float* wp = ((nl < 128) ? Wg : Wu) + n0g + cl;
    const int wstr = FF;

    const int ako = t & 7, am = t >> 3;
    const bf16* apt = A + (size_t)(m0 + am) * DM + ako * 8;

    const int wm = (w >> 2) * 128, wn = (w & 3) * 64;
    const int fr = lane & 15, sl = lane >> 4;

    f32x4 acc[8][4];
    f32x4 z = {0.f, 0.f, 0.f, 0.f};
    #pragma unroll
    for (int i = 0; i < 8; ++i)
        #pragma unroll
        for (int j = 0; j < 4; ++j) acc[i][j] = z;

    float rb[4][8];
    s8v ra[4];

    auto LOADR = [&](int tile) {
        const int k0 = tile * 64;
        #pragma unroll
        for (int u = 0; u < 4; ++u) {
            const float* p = wp + (size_t)(k0 + (kob + 2 * u) * 8) * wstr;
            #pragma unroll
            for (int j = 0; j < 8; ++j) rb[u][j] = p[(size_t)j * wstr];
            ra[u] = *(const s8v*)(apt + (size_t)(64 * u) * DM + k0);
        }
    };
    auto WRITE = [&](char* AsB, char* BsB) {
        #pragma unroll
        for (int u = 0; u < 4; ++u) {
            union { bf16 h[8]; s8v v; } cv;
            #pragma unroll
            for (int j = 0; j < 8; ++j) cv.h[j] = __float2bfloat16(rb[u][j]);
            int ko = kob + 2 * u;
            *(s8v*)(BsB + nl * 128 + ((ko * 16) ^ ((nl & 7) << 4))) = cv.v;
            int m = am + 64 * u;
            *(s8v*)(AsB + m * 128 + ((ako * 16) ^ ((m & 7) << 4))) = ra[u];
        }
    };
    auto COMPUTE = [&](const char* AsB, const char* BsB) {
        #pragma unroll
        for (int kk = 0; kk < 2; ++kk) {
            const int kb = kk * 64 + sl * 16;
            s8v af[8], bfv[4];
            #pragma unroll
            for (int i = 0; i < 8; ++i) {
                int m = wm + i * 16 + fr;
                af[i] = *(const s8v*)(AsB + m * 128 + (kb ^ ((m & 7) << 4)));
            }
            #pragma unroll
            for (int j = 0; j < 4; ++j) {
                int n = wn + j * 16 + fr;
                bfv[j] = *(const s8v*)(BsB + n * 128 + (kb ^ ((n & 7) << 4)));
            }
            #pragma unroll
            for (int i = 0; i < 8; ++i)
                #pragma unroll
                for (int j = 0; j < 4; ++j)
                    acc[i][j] = __builtin_amdgcn_mfma_f32_16x16x32_bf16(af[i], bfv[j], acc[i][j], 0, 0, 0);
        }
    };

    const int nt = DM / 64;
    LOADR(0);
    WRITE(lds, lds + 65536);
    __syncthreads();
    for (int tt = 0; tt < nt; ++tt) {
        const int cur = tt & 1;
        if (tt + 1 < nt) LOADR(tt + 1);
        COMPUTE(lds + cur * 32768, lds + 65536 + cur * 32768);
        if (tt + 1 < nt) {
            __syncthreads();
            WRITE(lds + (cur ^ 1) * 32768, lds + 65536 + (cur ^ 1) * 32768);
            __syncthreads();
        }
    }

    __syncthreads();
    bf16* Ups = (bf16*)lds;    // [256][130]
    if (wn >= 128) {
        #pragma unroll
        for (int i = 0; i < 8; ++i) {
            #pragma unroll
            for (int j = 0; j < 4; ++j) {
                #pragma unroll
                for (int q = 0; q < 4; ++q) {
                    int row = wm + i * 16 + sl * 4 + q;
                    int col = (wn - 128) + j * 16 + fr;
                    Ups[row * 130 + col] = __float2bfloat16(acc[i][j][q]);
                }
            }
        }
    }
    __syncthreads();
    if (wn < 128) {
        #pragma unroll
        for (int i = 0; i < 8; ++i) {
            #pragma unroll
            for (int j = 0; j < 4; ++j) {
                #pragma unroll
                for (int q = 0; q < 4; ++q) {
                    int row = wm + i * 16 + sl * 4 + q;
                    int col = wn + j * 16 + fr;
                    float g = acc[i][j][q];
                    float u = __bfloat162float(Ups[row * 130 + col]);
                    gab[(size_t)(m0 + row) * FF + n0g + col] =
                        __float2bfloat16(g / (1.f + expf(-g)) * u);
                }
            }
        }
    }
}

// ---------------- split-K reduce (plain; final down-reduce) ----------------
__global__ __launch_bounds__(256) void reduceN_kernel(float* __restrict__ dst,
                                                      const float* __restrict__ p,
                                                      int n4, int slices, int addto,
                                                      size_t stride4) {
    int i = blockIdx.x * 256 + threadIdx.x;
    if (i >= n4) return;
    float4 a;
    if (addto) a = ((const float4*)dst)[i];
    else { a.x = a.y = a.z = a.w = 0.f; }
    for (int c = 0; c < slices; ++c) {
        float4 v = ((const float4*)p)[i + c * stride4];
        a.x += v.x; a.y += v.y; a.z += v.z; a.w += v.w;
    }
    ((float4*)dst)[i] = a;
}

// ---------------- merged RoPE + V-transpose from qkv psum slices ----------------
__global__ __launch_bounds__(256) void rope_vtrans_kernel(const float* __restrict__ p0,
                                                          const float* __restrict__ p1,
                                                          bf16* __restrict__ Qh,
                                                          bf16* __restrict__ Kh,
                                                          bf16* __restrict__ Vt) {
    __shared__ float tile[64][65];
    if (blockIdx.x < ROPE_BLOCKS) {
        int idx = blockIdx.x * 256 + threadIdx.x;
        int i = idx & 31;
        int hh = (idx >> 5) % (NH + NKVH);
        int s = idx / (32 * (NH + NKVH));
        bool isq = hh < NH;
        int col = isq ? hh * HD + i : DM + (hh - NH) * HD + i;
        size_t off = (size_t)s * QKVW + col;
        float a = p0[off] + p1[off];
        float b = p0[off + 32] + p1[off + 32];
        float inv = exp2f(-(float)i * 0.41524101186092029f);
        float ang = (float)s * inv;
        float c = cosf(ang), sn = sinf(ang);
        float ra = a * c - b * sn;
        float rb = b * c + a * sn;
        if (isq) {
            bf16* p = Qh + ((size_t)hh * SEQ + s) * HD + i;
            p[0]  = __float2bfloat16(ra);
            p[32] = __float2bfloat16(rb);
        } else {
            bf16* p = Kh + ((size_t)(hh - NH) * SEQ + s) * HD + i;
            p[0]  = __float2bfloat16(ra);
            p[32] = __float2bfloat16(rb);
        }
    } else {
        int bx = blockIdx.x - ROPE_BLOCKS;       // 0..127
        const int s0 = (bx & 15) * 64;
        const int kvh = bx >> 4;
        const int tx = threadIdx.x & 63, ty = threadIdx.x >> 6;
        #pragma unroll
        for (int i = 0; i < 16; ++i) {
            size_t off = (size_t)(s0 + i * 4 + ty) * QKVW + DM + 512 + kvh * HD + tx;
            tile[i * 4 + ty][tx] = p0[off] + p1[off];
        }
        __syncthreads();
        #pragma unroll
        for (int i = 0; i < 16; ++i) {
            int d = i * 4 + ty;
            Vt[((size_t)kvh * HD + d) * SEQ + s0 + tx] = __float2bfloat16(tile[tx][d]);
        }
    }
}

// ---------------- MFMA flash attention: heavy q-tiles dispatch first ----------------
__global__ __launch_bounds__(256) void attn_mfma_kernel(const bf16* __restrict__ Qh,
                                                        const bf16* __restrict__ Kh,
                                                        const bf16* __restrict__ Vt,
                                                        bf16* __restrict__ o) {
    __shared__ char lds[32768];
    char* Qs = lds;
    char* Ks = lds + 8192;
    char* Vs = lds + 16384;
    char* Ps = lds + 24576;
    const int t = threadIdx.x, lane = t & 63, w = t >> 6;
    const int g = lane >> 4, lo = lane & 15;
    const int h = blockIdx.y, kvh = h >> 2;
    const int qt = gridDim.x - 1 - blockIdx.x;
    const int qbase = qt * 64;
    const int strip = w * 16;
    const bf16* qsrc = Qh + ((size_t)h * SEQ + qbase) * HD;
    const bf16* ksrc = Kh + (size_t)kvh * SEQ * HD;
    const bf16* vsrc = Vt + (size_t)kvh * HD * SEQ;

    #pragma unroll
    for (int c = t; c < 512; c += 256) {
        int row = c >> 3, col = c & 7;
        *(s8v*)(Qs + row * 128 + ((col * 16) ^ ((row & 7) << 4))) =
            *(const s8v*)(qsrc + row * HD + col * 8);
    }

    f32x4 oacc[4];
    f32x4 z = {0.f, 0.f, 0.f, 0.f};
    #pragma unroll
    for (int dj = 0; dj < 4; ++dj) oacc[dj] = z;
    float m0[4], lsum[4];
    #pragma unroll
    for (int r = 0; r < 4; ++r) { m0[r] = -INFINITY; lsum[r] = 0.f; }

    for (int kt = 0; kt <= qt; ++kt) {
        __syncthreads();
        const bf16* kq = ksrc + (size_t)(kt * 64) * HD;
        const bf16* vq = vsrc + kt * 64;
        #pragma unroll
        for (int c = t; c < 512; c += 256) {
            int row = c >> 3, col = c & 7;
            int swz = (col * 16) ^ ((row & 7) << 4);
            *(s8v*)(Ks + row * 128 + swz) = *(const s8v*)(kq + row * HD + col * 8);
            *(s8v*)(Vs + row * 128 + swz) = *(const s8v*)(vq + (size_t)row * SEQ + col * 8);
        }
        __syncthreads();

        s8v qa0 = *(const s8v*)(Qs + (strip + lo) * 128 + ((g * 16) ^ ((lo & 7) << 4)));
        s8v qa1 = *(const s8v*)(Qs + (strip + lo) * 128 + ((64 + g * 16) ^ ((lo & 7) << 4)));
        f32x4 sacc[4];
        #pragma unroll
        for (int j = 0; j < 4; ++j) {
            s8v kb0 = *(const s8v*)(Ks + (j * 16 + lo) * 128 + ((g * 16) ^ ((lo & 7) << 4)));
            s8v kb1 = *(const s8v*)(Ks + (j * 16 + lo) * 128 + ((64 + g * 16) ^ ((lo & 7) << 4)));
            f32x4 sv = __builtin_amdgcn_mfma_f32_16x16x32_bf16(qa0, kb0, z, 0, 0, 0);
            sacc[j] = __builtin_amdgcn_mfma_f32_16x16x32_bf16(qa1, kb1, sv, 0, 0, 0);
        }
        #pragma unroll
        for (int j = 0; j < 4; ++j) {
            int kgl = kt * 64 + j * 16 + lo;
            #pragma unroll
            for (int r = 0; r < 4; ++r) {
                int qgl = qbase + strip + g * 4 + r;
                float sv = sacc[j][r] * 0.125f;
                sacc[j][r] = (kgl <= qgl) ? sv : -INFINITY;
            }
        }
        float rmax[4], resc[4];
        #pragma unroll
        for (int r = 0; r < 4; ++r) {
            float mx = fmaxf(fmaxf(sacc[0][r], sacc[1][r]), fmaxf(sacc[2][r], sacc[3][r]));
            mx = fmaxf(mx, __shfl_xor(mx, 1, 64));
            mx = fmaxf(mx, __shfl_xor(mx, 2, 64));
            mx = fmaxf(mx, __shfl_xor(mx, 4, 64));
            mx = fmaxf(mx, __shfl_xor(mx, 8, 64));
            float mn = fmaxf(m0[r], mx);
            resc[r] = expf(m0[r] - mn);
            m0[r] = mn;
            rmax[r] = mn;
        }
        #pragma unroll
        for (int j = 0; j < 4; ++j)
            #pragma unroll
            for (int r = 0; r < 4; ++r)
                sacc[j][r] = expf(sacc[j][r] - rmax[r]);
        #pragma unroll
        for (int r = 0; r < 4; ++r) {
            float ps = sacc[0][r] + sacc[1][r] + sacc[2][r] + sacc[3][r];
            lsum[r] = lsum[r] * resc[r] + ps;
        }
        #pragma unroll
        for (int dj = 0; dj < 4; ++dj)
            #pragma unroll
            for (int r = 0; r < 4; ++r)
                oacc[dj][r] *= resc[r];
        #pragma unroll
        for (int j = 0; j < 4; ++j) {
            #pragma unroll
            for (int r = 0; r < 4; ++r) {
                int prow = strip + g * 4 + r;
                int pcol = j * 16 + lo;
                *(bf16*)(Ps + prow * 128 + ((pcol * 2) ^ ((prow & 7) << 4))) =
                    __float2bfloat16(sacc[j][r]);
            }
        }
        s8v pa0 = *(const s8v*)(Ps + (strip + lo) * 128 + ((g * 16) ^ ((lo & 7) << 4)));
        s8v pa1 = *(const s8v*)(Ps + (strip + lo) * 128 + ((64 + g * 16) ^ ((lo & 7) << 4)));
        #pragma unroll
        for (int dj = 0; dj < 4; ++dj) {
            s8v vb0 = *(const s8v*)(Vs + (dj * 16 + lo) * 128 + ((g * 16) ^ ((lo & 7) << 4)));
            s8v vb1 = *(const s8v*)(Vs + (dj * 16 + lo) * 128 + ((64 + g * 16) ^ ((lo & 7) << 4)));
            oacc[dj] = __builtin_amdgcn_mfma_f32_16x16x32_bf16(pa0, vb0, oacc[dj], 0, 0, 0);
            oacc[dj] = __builtin_amdgcn_mfma_f32_16x16x32_bf16(pa1, vb1, oacc[dj], 0, 0, 0);
        }
    }
    float invl[4];
    #pragma unroll
    for (int r = 0; r < 4; ++r) {
        float l = lsum[r];
        l += __shfl_xor(l, 1, 64);
        l += __shfl_xor(l, 2, 64);
        l += __shfl_xor(l, 4, 64);
        l += __shfl_xor(l, 8, 64);
        invl[r] = 1.f / l;
    }
    #pragma unroll
    for (int dj = 0; dj < 4; ++dj) {
        #pragma unroll
        for (int r = 0; r < 4; ++r) {
            int qrow = qbase + strip + g * 4 + r;
            o[(size_t)qrow * DM + h * HD + dj * 16 + lo] =
                __float2bfloat16(oacc[dj][r] * invl[r]);
        }
    }
}

extern "C" void kernel_launch(void* const* d_in, const int* in_sizes, int n_in,
                              void* d_out, int out_size, void* d_ws, size_t ws_size,
                              hipStream_t stream) {
    const int*   ids   = (const int*)d_in[0];
    const float* emb   = (const float*)d_in[1];
    const float* wq    = (const float*)d_in[2];
    const float* wk    = (const float*)d_in[3];
    const float* wv    = (const float*)d_in[4];
    const float* wo    = (const float*)d_in[5];
    const float* wgate = (const float*)d_in[6];
    const float* wup   = (const float*)d_in[7];
    const float* wdown = (const float*)d_in[8];
    const float* ln1   = (const float*)d_in[9];
    const float* ln2   = (const float*)d_in[10];
    float* x = (float*)d_out;

    bf16* h_bf  = (bf16*)d_ws;
    bf16* attnb = h_bf  + (size_t)SEQ * DM;
    bf16* gab   = attnb + (size_t)SEQ * DM;
    bf16* Qhb   = gab   + (size_t)SEQ * FF;
    bf16* Khb   = Qhb   + (size_t)NH * SEQ * HD;
    bf16* Vtb   = Khb   + (size_t)NKVH * SEQ * HD;
    float* psum = (float*)(Vtb + (size_t)NKVH * HD * SEQ);

    embed_kernel<<<SEQ, 256, 0, stream>>>(ids, emb, x);
    rms_kernel<<<SEQ, 256, 0, stream>>>(x, ln1, h_bf);   // layer-0 ln1

    for (int l = 0; l < NL; ++l) {
        const float* wq_l = wq + (size_t)l * DM * DM;
        const float* wk_l = wk + (size_t)l * DM * 512;
        const float* wv_l = wv + (size_t)l * DM * 512;
        const float* wo_l = wo + (size_t)l * DM * DM;
        const float* wg_l = wgate + (size_t)l * DM * FF;
        const float* wu_l = wup   + (size_t)l * DM * FF;
        const float* wd_l = wdown + (size_t)l * FF * DM;

        // qkv: fused wq|wk|wv, split-K x2 -> psum slices (h_bf already holds rms(x, ln1[l]))
        gemm_f32w_kernel<false><<<dim3(QKVW / 128, SEQ / 128, 2), 256, 0, stream>>>(
            h_bf, DM, wq_l, DM, wk_l, 512, wv_l, psum, nullptr, SEQ, QKVW, DM / 2);

        rope_vtrans_kernel<<<ROPE_BLOCKS + 128, 256, 0, stream>>>(
            psum, psum + (size_t)SEQ * QKVW, Qhb, Khb, Vtb);

        attn_mfma_kernel<<<dim3(SEQ / 64, NH), 256, 0, stream>>>(Qhb, Khb, Vtb, attnb);

        // wo: 256-tile split-K x8 (256 blocks) -> psum; fused: x += sum; h_bf = rms(x, ln2[l])
        gemm256_kernel<<<dim3(DM / 256, SEQ / 256, 8), 512, 0, stream>>>(
            attnb, DM, wo_l, DM, nullptr, psum, SEQ, DM, DM / 8);
        reduce_rms_kernel<<<SEQ, 256, 0, stream>>>(
            x, psum, 8, (size_t)SEQ * DM / 4, ln2 + (size_t)l * DM, h_bf);

        // gate|up + fused SiLU -> gab
        gemm_gu_kernel<<<dim3(FF / 128, SEQ / 256), 512, 0, stream>>>(
            h_bf, wg_l, wu_l, gab);

        // down: 256-tile split-K x8 -> psum
        gemm256_kernel<<<dim3(DM / 256, SEQ / 256, 8), 512, 0, stream>>>(
            gab, FF, wd_l, DM, nullptr, psum, SEQ, DM, FF / 8);
        if (l + 1 < NL) {
            reduce_rms_kernel<<<SEQ, 256, 0, stream>>>(
                x, psum, 8, (size_t)SEQ * DM / 4, ln1 + (size_t)(l + 1) * DM, h_bf);
        } else {
            reduceN_kernel<<<(SEQ * DM / 4 + 255) / 256, 256, 0, stream>>>(
                x, psum, SEQ * DM / 4, 8, 1, (size_t)SEQ * DM / 4);
        }
    }
}

// Round 19
// 557.896 us; speedup vs baseline: 1.0201x; 1.0201x over previous
//
#include <hip/hip_runtime.h>
#include <hip/hip_bf16.h>
#include <math.h>

#define NL 2
#define NH 32
#define NKVH 8
#define HD 64
#define DM 2048
#define FF 8192
#define SEQ 1024
#define QKVW 3072
#define RMS_EPS 1e-5f
#define ROPE_BLOCKS (SEQ * (NH + NKVH) * 32 / 256)   // 5120

typedef short s8v __attribute__((ext_vector_type(8)));
typedef short s4v __attribute__((ext_vector_type(4)));
typedef float f32x4 __attribute__((ext_vector_type(4)));
typedef __hip_bfloat16 bf16;

// ---------------- embed gather ----------------
__global__ __launch_bounds__(256) void embed_kernel(const int* __restrict__ ids,
                                                    const float* __restrict__ emb,
                                                    float* __restrict__ x) {
    int s = blockIdx.x;
    int row = ids[s];
    const float4* src = (const float4*)(emb + (size_t)row * DM);
    float4* dst = (float4*)(x + (size_t)s * DM);
    #pragma unroll
    for (int i = 0; i < 2; ++i)
        dst[threadIdx.x + i * 256] = src[threadIdx.x + i * 256];
}

// ---------------- RMSNorm: f32 in, bf16 out ----------------
__global__ __launch_bounds__(256) void rms_kernel(const float* __restrict__ x,
                                                  const float* __restrict__ g,
                                                  bf16* __restrict__ out) {
    int s = blockIdx.x;
    const float4* row = (const float4*)(x + (size_t)s * DM);
    float4 v0 = row[threadIdx.x * 2];
    float4 v1 = row[threadIdx.x * 2 + 1];
    float ss = v0.x*v0.x + v0.y*v0.y + v0.z*v0.z + v0.w*v0.w
             + v1.x*v1.x + v1.y*v1.y + v1.z*v1.z + v1.w*v1.w;
    #pragma unroll
    for (int o = 32; o > 0; o >>= 1) ss += __shfl_down(ss, o, 64);
    __shared__ float red[4];
    if ((threadIdx.x & 63) == 0) red[threadIdx.x >> 6] = ss;
    __syncthreads();
    float total = red[0] + red[1] + red[2] + red[3];
    float inv = 1.0f / sqrtf(total / (float)DM + RMS_EPS);
    const float4* g4 = (const float4*)g;
    float4 ga = g4[threadIdx.x * 2], gb = g4[threadIdx.x * 2 + 1];
    union { bf16 h[8]; s8v v; } u;
    u.h[0] = __float2bfloat16(v0.x * inv * ga.x);
    u.h[1] = __float2bfloat16(v0.y * inv * ga.y);
    u.h[2] = __float2bfloat16(v0.z * inv * ga.z);
    u.h[3] = __float2bfloat16(v0.w * inv * ga.w);
    u.h[4] = __float2bfloat16(v1.x * inv * gb.x);
    u.h[5] = __float2bfloat16(v1.y * inv * gb.y);
    u.h[6] = __float2bfloat16(v1.z * inv * gb.z);
    u.h[7] = __float2bfloat16(v1.w * inv * gb.w);
    *(s8v*)(out + (size_t)s * DM + threadIdx.x * 8) = u.v;
}

// ---------------- fused split-K reduce + residual add + RMSNorm ----------------
__global__ __launch_bounds__(256) void reduce_rms_kernel(float* __restrict__ x,
                                                         const float* __restrict__ p,
                                                         int slices, size_t stride4,
                                                         const float* __restrict__ g,
                                                         bf16* __restrict__ out) {
    const int s = blockIdx.x, t = threadIdx.x;
    const size_t i0 = (size_t)s * (DM / 4) + t * 2;
    float4 v0 = ((const float4*)x)[i0];
    float4 v1 = ((const float4*)x)[i0 + 1];
    for (int c = 0; c < slices; ++c) {
        float4 a = ((const float4*)p)[i0 + c * stride4];
        float4 b = ((const float4*)p)[i0 + 1 + c * stride4];
        v0.x += a.x; v0.y += a.y; v0.z += a.z; v0.w += a.w;
        v1.x += b.x; v1.y += b.y; v1.z += b.z; v1.w += b.w;
    }
    ((float4*)x)[i0] = v0;
    ((float4*)x)[i0 + 1] = v1;
    float ss = v0.x*v0.x + v0.y*v0.y + v0.z*v0.z + v0.w*v0.w
             + v1.x*v1.x + v1.y*v1.y + v1.z*v1.z + v1.w*v1.w;
    #pragma unroll
    for (int o = 32; o > 0; o >>= 1) ss += __shfl_down(ss, o, 64);
    __shared__ float red[4];
    if ((t & 63) == 0) red[t >> 6] = ss;
    __syncthreads();
    float total = red[0] + red[1] + red[2] + red[3];
    float inv = 1.0f / sqrtf(total / (float)DM + RMS_EPS);
    const float4* g4 = (const float4*)g;
    float4 ga = g4[t * 2], gb = g4[t * 2 + 1];
    union { bf16 h[8]; s8v v; } u;
    u.h[0] = __float2bfloat16(v0.x * inv * ga.x);
    u.h[1] = __float2bfloat16(v0.y * inv * ga.y);
    u.h[2] = __float2bfloat16(v0.z * inv * ga.z);
    u.h[3] = __float2bfloat16(v0.w * inv * ga.w);
    u.h[4] = __float2bfloat16(v1.x * inv * gb.x);
    u.h[5] = __float2bfloat16(v1.y * inv * gb.y);
    u.h[6] = __float2bfloat16(v1.z * inv * gb.z);
    u.h[7] = __float2bfloat16(v1.w * inv * gb.w);
    *(s8v*)(out + (size_t)s * DM + t * 8) = u.v;
}

// ---------------- bf16 MFMA GEMM with in-kernel f32-weight transpose (128x128x64) ----------------
template<bool OUTBF>
__global__ __launch_bounds__(256) void gemm_f32w_kernel(const bf16* __restrict__ A, int Ka,
                                                        const float* __restrict__ Wa, int Na,
                                                        const float* __restrict__ Wb, int Nb,
                                                        const float* __restrict__ Wc,
                                                        float* __restrict__ C,
                                                        bf16* __restrict__ Cb,
                                                        int M, int N, int Kchunk) {
    __shared__ bf16 As[2][128 * 64];
    __shared__ bf16 Bs[2][128 * 64];
    const int t = threadIdx.x, lane = t & 63;
    const int w = t >> 6;
    const int m0 = blockIdx.y * 128, n0 = blockIdx.x * 128;
    const size_t koff = (size_t)blockIdx.z * Kchunk;

    const int nl = t & 127;
    const int kob = t >> 7;
    const int ng = n0 + nl;
    const float* wp; int wstr;
    if (ng < Na)           { wp = Wa + ng;             wstr = Na; }
    else if (ng < Na + Nb) { wp = Wb + (ng - Na);      wstr = Nb; }
    else                   { wp = Wc + (ng - Na - Nb); wstr = N - Na - Nb; }
    wp += koff * (size_t)wstr;

    const int ako = t & 7, am = t >> 3;
    const bf16* apt = A + (size_t)(m0 + am) * Ka + koff + ako * 8;

    const int wm = (w >> 1) * 64, wn = (w & 1) * 64;
    const int fr = lane & 15, sl = lane >> 4;

    f32x4 acc[4][4];
    f32x4 z = {0.f, 0.f, 0.f, 0.f};
    #pragma unroll
    for (int i = 0; i < 4; ++i)
        #pragma unroll
        for (int j = 0; j < 4; ++j) acc[i][j] = z;

    float rb[4][8];
    s8v ra[4];

    auto LOADR = [&](int tile) {
        const int k0 = tile * 64;
        #pragma unroll
        for (int u = 0; u < 4; ++u) {
            const float* p = wp + (size_t)(k0 + (kob + 2 * u) * 8) * wstr;
            #pragma unroll
            for (int j = 0; j < 8; ++j) rb[u][j] = p[(size_t)j * wstr];
            ra[u] = *(const s8v*)(apt + (size_t)(32 * u) * Ka + k0);
        }
    };
    auto WRITE = [&](bf16* AsB, bf16* BsB) {
        #pragma unroll
        for (int u = 0; u < 4; ++u) {
            union { bf16 h[8]; s8v v; } cv;
            #pragma unroll
            for (int j = 0; j < 8; ++j) cv.h[j] = __float2bfloat16(rb[u][j]);
            int ko = kob + 2 * u;
            *(s8v*)((char*)BsB + nl * 128 + ((ko * 16) ^ ((nl & 7) << 4))) = cv.v;
            int m = am + 32 * u;
            *(s8v*)((char*)AsB + m * 128 + ((ako * 16) ^ ((m & 7) << 4))) = ra[u];
        }
    };
    auto COMPUTE = [&](const bf16* AsB, const bf16* BsB) {
        #pragma unroll
        for (int kk = 0; kk < 2; ++kk) {
            const int kb = kk * 64 + sl * 16;
            s8v af[4], bfv[4];
            #pragma unroll
            for (int i = 0; i < 4; ++i) {
                int m = wm + i * 16 + fr;
                af[i] = *(const s8v*)((const char*)AsB + m * 128 + (kb ^ ((m & 7) << 4)));
            }
            #pragma unroll
            for (int j = 0; j < 4; ++j) {
                int n = wn + j * 16 + fr;
                bfv[j] = *(const s8v*)((const char*)BsB + n * 128 + (kb ^ ((n & 7) << 4)));
            }
            #pragma unroll
            for (int i = 0; i < 4; ++i)
                #pragma unroll
                for (int j = 0; j < 4; ++j)
                    acc[i][j] = __builtin_amdgcn_mfma_f32_16x16x32_bf16(af[i], bfv[j], acc[i][j], 0, 0, 0);
        }
    };

    const int nt = Kchunk / 64;
    LOADR(0);
    WRITE(&As[0][0], &Bs[0][0]);
    __syncthreads();
    for (int tt = 0; tt < nt; ++tt) {
        const int cur = tt & 1;
        if (tt + 1 < nt) LOADR(tt + 1);
        COMPUTE(&As[cur][0], &Bs[cur][0]);
        if (tt + 1 < nt) {
            __syncthreads();
            WRITE(&As[cur ^ 1][0], &Bs[cur ^ 1][0]);
            __syncthreads();
        }
    }

    float* Cz = C + (size_t)blockIdx.z * M * N;
    #pragma unroll
    for (int i = 0; i < 4; ++i) {
        #pragma unroll
        for (int j = 0; j < 4; ++j) {
            #pragma unroll
            for (int q = 0; q < 4; ++q) {
                int row = m0 + wm + i * 16 + sl * 4 + q;
                int col = n0 + wn + j * 16 + fr;
                float vv = acc[i][j][q];
                if constexpr (OUTBF) Cb[(size_t)row * N + col] = __float2bfloat16(vv);
                else                 Cz[(size_t)row * N + col] = vv;
            }
        }
    }
}

// ---------------- 256x256x64 8-wave GEMM, f32 weights in, f32 split-K partials (down) ----------------
__global__ __launch_bounds__(512) void gemm256_kernel(const bf16* __restrict__ A, int Ka,
                                                      const float* __restrict__ Wa, int Na,
                                                      const float* __restrict__ Wb,
                                                      float* __restrict__ C,
                                                      int M, int N, int Kchunk) {
    __shared__ bf16 As[2][256 * 64];
    __shared__ bf16 Bs[2][256 * 64];
    const int t = threadIdx.x, lane = t & 63;
    const int w = t >> 6;
    const int m0 = blockIdx.y * 256, n0 = blockIdx.x * 256;
    const size_t koff = (size_t)blockIdx.z * Kchunk;

    const int nl = t & 255;
    const int kob = t >> 8;
    const int ng = n0 + nl;
    const float* wp; int wstr;
    if (ng < Na) { wp = Wa + ng;        wstr = Na; }
    else         { wp = Wb + (ng - Na); wstr = N - Na; }
    wp += koff * (size_t)wstr;

    const int ako = t & 7, am = t >> 3;
    const bf16* apt = A + (size_t)(m0 + am) * Ka + koff + ako * 8;

    const int wm = (w >> 2) * 128, wn = (w & 3) * 64;
    const int fr = lane & 15, sl = lane >> 4;

    f32x4 acc[8][4];
    f32x4 z = {0.f, 0.f, 0.f, 0.f};
    #pragma unroll
    for (int i = 0; i < 8; ++i)
        #pragma unroll
        for (int j = 0; j < 4; ++j) acc[i][j] = z;

    float rb[4][8];
    s8v ra[4];

    auto LOADR = [&](int tile) {
        const int k0 = tile * 64;
        #pragma unroll
        for (int u = 0; u < 4; ++u) {
            const float* p = wp + (size_t)(k0 + (kob + 2 * u) * 8) * wstr;
            #pragma unroll
            for (int j = 0; j < 8; ++j) rb[u][j] = p[(size_t)j * wstr];
            ra[u] = *(const s8v*)(apt + (size_t)(64 * u) * Ka + k0);
        }
    };
    auto WRITE = [&](bf16* AsB, bf16* BsB) {
        #pragma unroll
        for (int u = 0; u < 4; ++u) {
            union { bf16 h[8]; s8v v; } cv;
            #pragma unroll
            for (int j = 0; j < 8; ++j) cv.h[j] = __float2bfloat16(rb[u][j]);
            int ko = kob + 2 * u;
            *(s8v*)((char*)BsB + nl * 128 + ((ko * 16) ^ ((nl & 7) << 4))) = cv.v;
            int m = am + 64 * u;
            *(s8v*)((char*)AsB + m * 128 + ((ako * 16) ^ ((m & 7) << 4))) = ra[u];
        }
    };
    auto COMPUTE = [&](const bf16* AsB, const bf16* BsB) {
        #pragma unroll
        for (int kk = 0; kk < 2; ++kk) {
            const int kb = kk * 64 + sl * 16;
            s8v af[8], bfv[4];
            #pragma unroll
            for (int i = 0; i < 8; ++i) {
                int m = wm + i * 16 + fr;
                af[i] = *(const s8v*)((const char*)AsB + m * 128 + (kb ^ ((m & 7) << 4)));
            }
            #pragma unroll
            for (int j = 0; j < 4; ++j) {
                int n = wn + j * 16 + fr;
                bfv[j] = *(const s8v*)((const char*)BsB + n * 128 + (kb ^ ((n & 7) << 4)));
            }
            #pragma unroll
            for (int i = 0; i < 8; ++i)
                #pragma unroll
                for (int j = 0; j < 4; ++j)
                    acc[i][j] = __builtin_amdgcn_mfma_f32_16x16x32_bf16(af[i], bfv[j], acc[i][j], 0, 0, 0);
        }
    };

    const int nt = Kchunk / 64;
    LOADR(0);
    WRITE(&As[0][0], &Bs[0][0]);
    __syncthreads();
    for (int tt = 0; tt < nt; ++tt) {
        const int cur = tt & 1;
        if (tt + 1 < nt) LOADR(tt + 1);
        COMPUTE(&As[cur][0], &Bs[cur][0]);
        if (tt + 1 < nt) {
            __syncthreads();
            WRITE(&As[cur ^ 1][0], &Bs[cur ^ 1][0]);
            __syncthreads();
        }
    }

    float* Cz = C + (size_t)blockIdx.z * M * N;
    #pragma unroll
    for (int i = 0; i < 8; ++i) {
        #pragma unroll
        for (int j = 0; j < 4; ++j) {
            #pragma unroll
            for (int q = 0; q < 4; ++q) {
                int row = m0 + wm + i * 16 + sl * 4 + q;
                int col = n0 + wn + j * 16 + fr;
                Cz[(size_t)row * N + col] = acc[i][j][q];
            }
        }
    }
}

// ---------------- 256-wide gate|up GEMM with fused SiLU epilogue -> gab bf16 ----------------
__global__ __launch_bounds__(512) void gemm_gu_kernel(const bf16* __restrict__ A,
                                                      const float* __restrict__ Wg,
                                                      const float* __restrict__ Wu,
                                                      bf16* __restrict__ gab) {
    __shared__ char lds[131072];
    const int t = threadIdx.x, lane = t & 63;
    const int w = t >> 6;
    const int m0 = blockIdx.y * 256, n0g = blockIdx.x * 128;

    const int nl = t & 255;
    const int kob = t >> 8;
    const int cl = nl & 127;
    const float* wp = ((nl < 128) ? Wg : Wu) + n0g + cl;
    const int wstr = FF;

    const int ako = t & 7, am = t >> 3;
    const bf16* apt = A + (size_t)(m0 + am) * DM + ako * 8;

    const int wm = (w >> 2) * 128, wn = (w & 3) * 64;
    const int fr = lane & 15, sl = lane >> 4;

    f32x4 acc[8][4];
    f32x4 z = {0.f, 0.f, 0.f, 0.f};
    #pragma unroll
    for (int i = 0; i < 8; ++i)
        #pragma unroll
        for (int j = 0; j < 4; ++j) acc[i][j] = z;

    float rb[4][8];
    s8v ra[4];

    auto LOADR = [&](int tile) {
        const int k0 = tile * 64;
        #pragma unroll
        for (int u = 0; u < 4; ++u) {
            const float* p = wp + (size_t)(k0 + (kob + 2 * u) * 8) * wstr;
            #pragma unroll
            for (int j = 0; j < 8; ++j) rb[u][j] = p[(size_t)j * wstr];
            ra[u] = *(const s8v*)(apt + (size_t)(64 * u) * DM + k0);
        }
    };
    auto WRITE = [&](char* AsB, char* BsB) {
        #pragma unroll
        for (int u = 0; u < 4; ++u) {
            union { bf16 h[8]; s8v v; } cv;
            #pragma unroll
            for (int j = 0; j < 8; ++j) cv.h[j] = __float2bfloat16(rb[u][j]);
            int ko = kob + 2 * u;
            *(s8v*)(BsB + nl * 128 + ((ko * 16) ^ ((nl & 7) << 4))) = cv.v;
            int m = am + 64 * u;
            *(s8v*)(AsB + m * 128 + ((ako * 16) ^ ((m & 7) << 4))) = ra[u];
        }
    };
    auto COMPUTE = [&](const char* AsB, const char* BsB) {
        #pragma unroll
        for (int kk = 0; kk < 2; ++kk) {
            const int kb = kk * 64 + sl * 16;
            s8v af[8], bfv[4];
            #pragma unroll
            for (int i = 0; i < 8; ++i) {
                int m = wm + i * 16 + fr;
                af[i] = *(const s8v*)(AsB + m * 128 + (kb ^ ((m & 7) << 4)));
            }
            #pragma unroll
            for (int j = 0; j < 4; ++j) {
                int n = wn + j * 16 + fr;
                bfv[j] = *(const s8v*)(BsB + n * 128 + (kb ^ ((n & 7) << 4)));
            }
            #pragma unroll
            for (int i = 0; i < 8; ++i)
                #pragma unroll
                for (int j = 0; j < 4; ++j)
                    acc[i][j] = __builtin_amdgcn_mfma_f32_16x16x32_bf16(af[i], bfv[j], acc[i][j], 0, 0, 0);
        }
    };

    const int nt = DM / 64;
    LOADR(0);
    WRITE(lds, lds + 65536);
    __syncthreads();
    for (int tt = 0; tt < nt; ++tt) {
        const int cur = tt & 1;
        if (tt + 1 < nt) LOADR(tt + 1);
        COMPUTE(lds + cur * 32768, lds + 65536 + cur * 32768);
        if (tt + 1 < nt) {
            __syncthreads();
            WRITE(lds + (cur ^ 1) * 32768, lds + 65536 + (cur ^ 1) * 32768);
            __syncthreads();
        }
    }

    __syncthreads();
    bf16* Ups = (bf16*)lds;    // [256][130]
    if (wn >= 128) {
        #pragma unroll
        for (int i = 0; i < 8; ++i) {
            #pragma unroll
            for (int j = 0; j < 4; ++j) {
                #pragma unroll
                for (int q = 0; q < 4; ++q) {
                    int row = wm + i * 16 + sl * 4 + q;
                    int col = (wn - 128) + j * 16 + fr;
                    Ups[row * 130 + col] = __float2bfloat16(acc[i][j][q]);
                }
            }
        }
    }
    __syncthreads();
    if (wn < 128) {
        #pragma unroll
        for (int i = 0; i < 8; ++i) {
            #pragma unroll
            for (int j = 0; j < 4; ++j) {
                #pragma unroll
                for (int q = 0; q < 4; ++q) {
                    int row = wm + i * 16 + sl * 4 + q;
                    int col = wn + j * 16 + fr;
                    float g = acc[i][j][q];
                    float u = __bfloat162float(Ups[row * 130 + col]);
                    gab[(size_t)(m0 + row) * FF + n0g + col] =
                        __float2bfloat16(g / (1.f + expf(-g)) * u);
                }
            }
        }
    }
}

// ---------------- split-K reduce (plain; final down-reduce) ----------------
__global__ __launch_bounds__(256) void reduceN_kernel(float* __restrict__ dst,
                                                      const float* __restrict__ p,
                                                      int n4, int slices, int addto,
                                                      size_t stride4) {
    int i = blockIdx.x * 256 + threadIdx.x;
    if (i >= n4) return;
    float4 a;
    if (addto) a = ((const float4*)dst)[i];
    else { a.x = a.y = a.z = a.w = 0.f; }
    for (int c = 0; c < slices; ++c) {
        float4 v = ((const float4*)p)[i + c * stride4];
        a.x += v.x; a.y += v.y; a.z += v.z; a.w += v.w;
    }
    ((float4*)dst)[i] = a;
}

// ---------------- merged RoPE + V-transpose from qkv psum slices ----------------
__global__ __launch_bounds__(256) void rope_vtrans_kernel(const float* __restrict__ p0,
                                                          const float* __restrict__ p1,
                                                          bf16* __restrict__ Qh,
                                                          bf16* __restrict__ Kh,
                                                          bf16* __restrict__ Vt) {
    __shared__ float tile[64][65];
    if (blockIdx.x < ROPE_BLOCKS) {
        int idx = blockIdx.x * 256 + threadIdx.x;
        int i = idx & 31;
        int hh = (idx >> 5) % (NH + NKVH);
        int s = idx / (32 * (NH + NKVH));
        bool isq = hh < NH;
        int col = isq ? hh * HD + i : DM + (hh - NH) * HD + i;
        size_t off = (size_t)s * QKVW + col;
        float a = p0[off] + p1[off];
        float b = p0[off + 32] + p1[off + 32];
        float inv = exp2f(-(float)i * 0.41524101186092029f);
        float ang = (float)s * inv;
        float c = cosf(ang), sn = sinf(ang);
        float ra = a * c - b * sn;
        float rb = b * c + a * sn;
        if (isq) {
            bf16* p = Qh + ((size_t)hh * SEQ + s) * HD + i;
            p[0]  = __float2bfloat16(ra);
            p[32] = __float2bfloat16(rb);
        } else {
            bf16* p = Kh + ((size_t)(hh - NH) * SEQ + s) * HD + i;
            p[0]  = __float2bfloat16(ra);
            p[32] = __float2bfloat16(rb);
        }
    } else {
        int bx = blockIdx.x - ROPE_BLOCKS;       // 0..127
        const int s0 = (bx & 15) * 64;
        const int kvh = bx >> 4;
        const int tx = threadIdx.x & 63, ty = threadIdx.x >> 6;
        #pragma unroll
        for (int i = 0; i < 16; ++i) {
            size_t off = (size_t)(s0 + i * 4 + ty) * QKVW + DM + 512 + kvh * HD + tx;
            tile[i * 4 + ty][tx] = p0[off] + p1[off];
        }
        __syncthreads();
        #pragma unroll
        for (int i = 0; i < 16; ++i) {
            int d = i * 4 + ty;
            Vt[((size_t)kvh * HD + d) * SEQ + s0 + tx] = __float2bfloat16(tile[tx][d]);
        }
    }
}

// ---------------- MFMA flash attention: heavy q-tiles dispatch first ----------------
__global__ __launch_bounds__(256) void attn_mfma_kernel(const bf16* __restrict__ Qh,
                                                        const bf16* __restrict__ Kh,
                                                        const bf16* __restrict__ Vt,
                                                        bf16* __restrict__ o) {
    __shared__ char lds[32768];
    char* Qs = lds;
    char* Ks = lds + 8192;
    char* Vs = lds + 16384;
    char* Ps = lds + 24576;
    const int t = threadIdx.x, lane = t & 63, w = t >> 6;
    const int g = lane >> 4, lo = lane & 15;
    const int h = blockIdx.y, kvh = h >> 2;
    const int qt = gridDim.x - 1 - blockIdx.x;
    const int qbase = qt * 64;
    const int strip = w * 16;
    const bf16* qsrc = Qh + ((size_t)h * SEQ + qbase) * HD;
    const bf16* ksrc = Kh + (size_t)kvh * SEQ * HD;
    const bf16* vsrc = Vt + (size_t)kvh * HD * SEQ;

    #pragma unroll
    for (int c = t; c < 512; c += 256) {
        int row = c >> 3, col = c & 7;
        *(s8v*)(Qs + row * 128 + ((col * 16) ^ ((row & 7) << 4))) =
            *(const s8v*)(qsrc + row * HD + col * 8);
    }

    f32x4 oacc[4];
    f32x4 z = {0.f, 0.f, 0.f, 0.f};
    #pragma unroll
    for (int dj = 0; dj < 4; ++dj) oacc[dj] = z;
    float m0[4], lsum[4];
    #pragma unroll
    for (int r = 0; r < 4; ++r) { m0[r] = -INFINITY; lsum[r] = 0.f; }

    for (int kt = 0; kt <= qt; ++kt) {
        __syncthreads();
        const bf16* kq = ksrc + (size_t)(kt * 64) * HD;
        const bf16* vq = vsrc + kt * 64;
        #pragma unroll
        for (int c = t; c < 512; c += 256) {
            int row = c >> 3, col = c & 7;
            int swz = (col * 16) ^ ((row & 7) << 4);
            *(s8v*)(Ks + row * 128 + swz) = *(const s8v*)(kq + row * HD + col * 8);
            *(s8v*)(Vs + row * 128 + swz) = *(const s8v*)(vq + (size_t)row * SEQ + col * 8);
        }
        __syncthreads();

        s8v qa0 = *(const s8v*)(Qs + (strip + lo) * 128 + ((g * 16) ^ ((lo & 7) << 4)));
        s8v qa1 = *(const s8v*)(Qs + (strip + lo) * 128 + ((64 + g * 16) ^ ((lo & 7) << 4)));
        f32x4 sacc[4];
        #pragma unroll
        for (int j = 0; j < 4; ++j) {
            s8v kb0 = *(const s8v*)(Ks + (j * 16 + lo) * 128 + ((g * 16) ^ ((lo & 7) << 4)));
            s8v kb1 = *(const s8v*)(Ks + (j * 16 + lo) * 128 + ((64 + g * 16) ^ ((lo & 7) << 4)));
            f32x4 sv = __builtin_amdgcn_mfma_f32_16x16x32_bf16(qa0, kb0, z, 0, 0, 0);
            sacc[j] = __builtin_amdgcn_mfma_f32_16x16x32_bf16(qa1, kb1, sv, 0, 0, 0);
        }
        #pragma unroll
        for (int j = 0; j < 4; ++j) {
            int kgl = kt * 64 + j * 16 + lo;
            #pragma unroll
            for (int r = 0; r < 4; ++r) {
                int qgl = qbase + strip + g * 4 + r;
                float sv = sacc[j][r] * 0.125f;
                sacc[j][r] = (kgl <= qgl) ? sv : -INFINITY;
            }
        }
        float rmax[4], resc[4];
        #pragma unroll
        for (int r = 0; r < 4; ++r) {
            float mx = fmaxf(fmaxf(sacc[0][r], sacc[1][r]), fmaxf(sacc[2][r], sacc[3][r]));
            mx = fmaxf(mx, __shfl_xor(mx, 1, 64));
            mx = fmaxf(mx, __shfl_xor(mx, 2, 64));
            mx = fmaxf(mx, __shfl_xor(mx, 4, 64));
            mx = fmaxf(mx, __shfl_xor(mx, 8, 64));
            float mn = fmaxf(m0[r], mx);
            resc[r] = expf(m0[r] - mn);
            m0[r] = mn;
            rmax[r] = mn;
        }
        #pragma unroll
        for (int j = 0; j < 4; ++j)
            #pragma unroll
            for (int r = 0; r < 4; ++r)
                sacc[j][r] = expf(sacc[j][r] - rmax[r]);
        #pragma unroll
        for (int r = 0; r < 4; ++r) {
            float ps = sacc[0][r] + sacc[1][r] + sacc[2][r] + sacc[3][r];
            lsum[r] = lsum[r] * resc[r] + ps;
        }
        #pragma unroll
        for (int dj = 0; dj < 4; ++dj)
            #pragma unroll
            for (int r = 0; r < 4; ++r)
                oacc[dj][r] *= resc[r];
        #pragma unroll
        for (int j = 0; j < 4; ++j) {
            #pragma unroll
            for (int r = 0; r < 4; ++r) {
                int prow = strip + g * 4 + r;
                int pcol = j * 16 + lo;
                *(bf16*)(Ps + prow * 128 + ((pcol * 2) ^ ((prow & 7) << 4))) =
                    __float2bfloat16(sacc[j][r]);
            }
        }
        s8v pa0 = *(const s8v*)(Ps + (strip + lo) * 128 + ((g * 16) ^ ((lo & 7) << 4)));
        s8v pa1 = *(const s8v*)(Ps + (strip + lo) * 128 + ((64 + g * 16) ^ ((lo & 7) << 4)));
        #pragma unroll
        for (int dj = 0; dj < 4; ++dj) {
            s8v vb0 = *(const s8v*)(Vs + (dj * 16 + lo) * 128 + ((g * 16) ^ ((lo & 7) << 4)));
            s8v vb1 = *(const s8v*)(Vs + (dj * 16 + lo) * 128 + ((64 + g * 16) ^ ((lo & 7) << 4)));
            oacc[dj] = __builtin_amdgcn_mfma_f32_16x16x32_bf16(pa0, vb0, oacc[dj], 0, 0, 0);
            oacc[dj] = __builtin_amdgcn_mfma_f32_16x16x32_bf16(pa1, vb1, oacc[dj], 0, 0, 0);
        }
    }
    float invl[4];
    #pragma unroll
    for (int r = 0; r < 4; ++r) {
        float l = lsum[r];
        l += __shfl_xor(l, 1, 64);
        l += __shfl_xor(l, 2, 64);
        l += __shfl_xor(l, 4, 64);
        l += __shfl_xor(l, 8, 64);
        invl[r] = 1.f / l;
    }
    #pragma unroll
    for (int dj = 0; dj < 4; ++dj) {
        #pragma unroll
        for (int r = 0; r < 4; ++r) {
            int qrow = qbase + strip + g * 4 + r;
            o[(size_t)qrow * DM + h * HD + dj * 16 + lo] =
                __float2bfloat16(oacc[dj][r] * invl[r]);
        }
    }
}

extern "C" void kernel_launch(void* const* d_in, const int* in_sizes, int n_in,
                              void* d_out, int out_size, void* d_ws, size_t ws_size,
                              hipStream_t stream) {
    const int*   ids   = (const int*)d_in[0];
    const float* emb   = (const float*)d_in[1];
    const float* wq    = (const float*)d_in[2];
    const float* wk    = (const float*)d_in[3];
    const float* wv    = (const float*)d_in[4];
    const float* wo    = (const float*)d_in[5];
    const float* wgate = (const float*)d_in[6];
    const float* wup   = (const float*)d_in[7];
    const float* wdown = (const float*)d_in[8];
    const float* ln1   = (const float*)d_in[9];
    const float* ln2   = (const float*)d_in[10];
    float* x = (float*)d_out;

    bf16* h_bf  = (bf16*)d_ws;
    bf16* attnb = h_bf  + (size_t)SEQ * DM;
    bf16* gab   = attnb + (size_t)SEQ * DM;
    bf16* Qhb   = gab   + (size_t)SEQ * FF;
    bf16* Khb   = Qhb   + (size_t)NH * SEQ * HD;
    bf16* Vtb   = Khb   + (size_t)NKVH * SEQ * HD;
    float* psum = (float*)(Vtb + (size_t)NKVH * HD * SEQ);

    embed_kernel<<<SEQ, 256, 0, stream>>>(ids, emb, x);
    rms_kernel<<<SEQ, 256, 0, stream>>>(x, ln1, h_bf);   // layer-0 ln1

    for (int l = 0; l < NL; ++l) {
        const float* wq_l = wq + (size_t)l * DM * DM;
        const float* wk_l = wk + (size_t)l * DM * 512;
        const float* wv_l = wv + (size_t)l * DM * 512;
        const float* wo_l = wo + (size_t)l * DM * DM;
        const float* wg_l = wgate + (size_t)l * DM * FF;
        const float* wu_l = wup   + (size_t)l * DM * FF;
        const float* wd_l = wdown + (size_t)l * FF * DM;

        // qkv: fused wq|wk|wv, split-K x2 -> psum slices (h_bf already holds rms(x, ln1[l]))
        gemm_f32w_kernel<false><<<dim3(QKVW / 128, SEQ / 128, 2), 256, 0, stream>>>(
            h_bf, DM, wq_l, DM, wk_l, 512, wv_l, psum, nullptr, SEQ, QKVW, DM / 2);

        rope_vtrans_kernel<<<ROPE_BLOCKS + 128, 256, 0, stream>>>(
            psum, psum + (size_t)SEQ * QKVW, Qhb, Khb, Vtb);

        attn_mfma_kernel<<<dim3(SEQ / 64, NH), 256, 0, stream>>>(Qhb, Khb, Vtb, attnb);

        // wo: 128-tile split-K x4 -> psum; fused: x += sum; h_bf = rms(x, ln2[l])
        gemm_f32w_kernel<false><<<dim3(DM / 128, SEQ / 128, 4), 256, 0, stream>>>(
            attnb, DM, wo_l, DM, nullptr, 0, nullptr, psum, nullptr, SEQ, DM, DM / 4);
        reduce_rms_kernel<<<SEQ, 256, 0, stream>>>(
            x, psum, 4, (size_t)SEQ * DM / 4, ln2 + (size_t)l * DM, h_bf);

        // gate|up + fused SiLU -> gab
        gemm_gu_kernel<<<dim3(FF / 128, SEQ / 256), 512, 0, stream>>>(
            h_bf, wg_l, wu_l, gab);

        // down: 256-tile split-K x8 -> psum
        gemm256_kernel<<<dim3(DM / 256, SEQ / 256, 8), 512, 0, stream>>>(
            gab, FF, wd_l, DM, nullptr, psum, SEQ, DM, FF / 8);
        if (l + 1 < NL) {
            reduce_rms_kernel<<<SEQ, 256, 0, stream>>>(
                x, psum, 8, (size_t)SEQ * DM / 4, ln1 + (size_t)(l + 1) * DM, h_bf);
        } else {
            reduceN_kernel<<<(SEQ * DM / 4 + 255) / 256, 256, 0, stream>>>(
                x, psum, SEQ * DM / 4, 8, 1, (size_t)SEQ * DM / 4);
        }
    }
}